// Round 8
// baseline (144.198 us; speedup 1.0000x reference)
//
#include <hip/hip_runtime.h>
#include <math.h>

// WordLabelAttention on MI355X — Round 8: split-K attention + denser grids.
// N=4, H=8, D=64, E=512, KL=512, QROWS/n=2048.
//
//   kv_proj  : 512 blocks (32-row kl tiles). K -> Kp[nh][kl][d] bf16,
//              V -> Vt[nh][d][kl] bf16 (MFMA, weights cvt in-kernel).
//   attn     : SPLIT-K x2: 2048 blocks = 32 q-tiles(64) x 2 key-halves x 32 nh.
//              Each block: fused q-proj + 4 key-tile iters (LDS-staged K/V,
//              register prefetch). Deferred normalization => raw partials
//              combine linearly: writes O^T partial (bf16) + l (f32) to ws.
//              p = exp2(s), scale folded into Wq; mask bias as MFMA acc-init
//              (int4 broadcast loads). 4 blocks/CU.
//   out_gemm : 1024 blocks (64x64 tiles, 4/CU). At staging COMBINES the two
//              attention halves: A = (AO1+AO2) * 1/(l1+l2)  (head = k0>>6 is
//              chunk-uniform), then C = A @ Wo^T + bo.

typedef __bf16 bf16;
typedef __attribute__((ext_vector_type(8))) __bf16 bf16x8;
typedef __attribute__((ext_vector_type(4))) __bf16 bf16x4;
typedef __attribute__((ext_vector_type(4))) float f32x4;

#define LW 68  // LDS row stride (bf16) for Kt/Vs/At/Bt/Xk/Xv
#define LS 72  // LDS row stride for SX
#define QSCALE (0.044194173824159216f * 1.4426950408889634f)  // log2(e)/sqrt(512)
#define MASK_BIAS -64.0f

__device__ __forceinline__ bf16x8 cvt8(const float* p, float s) {
    float4 x0 = *(const float4*)p;
    float4 x1 = *(const float4*)(p + 4);
    return (bf16x8){(bf16)(x0.x * s), (bf16)(x0.y * s), (bf16)(x0.z * s), (bf16)(x0.w * s),
                    (bf16)(x1.x * s), (bf16)(x1.y * s), (bf16)(x1.z * s), (bf16)(x1.w * s)};
}

// ---------------------------------------------------------------- kv_proj
// grid 512 = 32 nh x 16 kl-tiles(32 rows). block 256 (w0-1: K, w2-3: V^T).
__global__ __launch_bounds__(256, 2) void kv_proj(const float* __restrict__ keys,
                                                  const float* __restrict__ values,
                                                  const float* __restrict__ Wk,
                                                  const float* __restrict__ Wv,
                                                  bf16* __restrict__ Kp,
                                                  bf16* __restrict__ Vt) {
    __shared__ bf16 Xk[32 * LW];
    __shared__ bf16 Xv[32 * LW];
    int t = threadIdx.x;
    int nh = blockIdx.x >> 4, klt = blockIdx.x & 15;
    int n = nh >> 3, h = nh & 7, kl0 = klt * 32;
    int w = t >> 6, quad = (t >> 4) & 3, c16 = t & 15;
#pragma unroll
    for (int i = 0; i < 2; ++i) {
        int f = t + i * 256, row = f >> 4, c4 = f & 15;  // 512 f4 slots over 32x16
        float4 a = *(const float4*)(keys + ((long)n * 512 + kl0 + row) * 512 + h * 64 + c4 * 4);
        float4 b = *(const float4*)(values + ((long)n * 512 + kl0 + row) * 512 + h * 64 + c4 * 4);
        *(bf16x4*)&Xk[row * LW + c4 * 4] = (bf16x4){(bf16)a.x, (bf16)a.y, (bf16)a.z, (bf16)a.w};
        *(bf16x4*)&Xv[row * LW + c4 * 4] = (bf16x4){(bf16)b.x, (bf16)b.y, (bf16)b.z, (bf16)b.w};
    }
    __syncthreads();
    if (w < 2) {
        // K: C[kl-row][d], wave w owns rows 16w..16w+15
        f32x4 acc[4];
#pragma unroll
        for (int nb = 0; nb < 4; ++nb) acc[nb] = (f32x4){0.f, 0.f, 0.f, 0.f};
#pragma unroll
        for (int kc = 0; kc < 2; ++kc) {
            bf16x8 a = *(const bf16x8*)&Xk[(16 * w + c16) * LW + 32 * kc + quad * 8];
#pragma unroll
            for (int nb = 0; nb < 4; ++nb) {
                bf16x8 b = cvt8(Wk + (16 * nb + c16) * 64 + 32 * kc + quad * 8, 1.0f);
                acc[nb] = __builtin_amdgcn_mfma_f32_16x16x32_bf16(a, b, acc[nb], 0, 0, 0);
            }
        }
#pragma unroll
        for (int nb = 0; nb < 4; ++nb)
#pragma unroll
            for (int r = 0; r < 4; ++r)
                Kp[((long)nh * 512 + kl0 + 16 * w + quad * 4 + r) * 64 + 16 * nb + c16] =
                    (bf16)acc[nb][r];
    } else {
        // V^T: C[d][kl-col], wave w2 owns d 32w2..32w2+31, kl cols 2 nb
        int w2 = w - 2;
        f32x4 acc[2][2];
#pragma unroll
        for (int mb = 0; mb < 2; ++mb)
#pragma unroll
            for (int nb = 0; nb < 2; ++nb) acc[mb][nb] = (f32x4){0.f, 0.f, 0.f, 0.f};
#pragma unroll
        for (int kc = 0; kc < 2; ++kc) {
#pragma unroll
            for (int mb = 0; mb < 2; ++mb) {
                bf16x8 a = cvt8(Wv + (32 * w2 + 16 * mb + c16) * 64 + 32 * kc + quad * 8, 1.0f);
#pragma unroll
                for (int nb = 0; nb < 2; ++nb) {
                    bf16x8 b = *(const bf16x8*)&Xv[(16 * nb + c16) * LW + 32 * kc + quad * 8];
                    acc[mb][nb] = __builtin_amdgcn_mfma_f32_16x16x32_bf16(a, b, acc[mb][nb], 0, 0, 0);
                }
            }
        }
#pragma unroll
        for (int mb = 0; mb < 2; ++mb)
#pragma unroll
            for (int nb = 0; nb < 2; ++nb)
#pragma unroll
                for (int r = 0; r < 4; ++r)
                    Vt[((long)nh * 64 + 32 * w2 + 16 * mb + quad * 4 + r) * 512 + kl0 + 16 * nb + c16] =
                        (bf16)acc[mb][nb][r];
    }
}

// ---------------------------------------------------------------- attn
// grid 2048 = 32 q-tiles x 2 halves x 32 nh (nh inner -> XCD K/V locality).
// block 256 (4 waves, 16 q-rows/wave), 4 key-tile iters per block.
__global__ __launch_bounds__(256, 4) void attn(const float* __restrict__ query,
                                               const float* __restrict__ Wq,
                                               const bf16* __restrict__ Kp,
                                               const bf16* __restrict__ Vtg,
                                               const int* __restrict__ maskp,
                                               bf16* __restrict__ AOp,
                                               float* __restrict__ Lb) {
    __shared__ bf16 SX[64 * LS];   // Xq -> Qt -> P (all rows wave-private)
    __shared__ bf16 Kt[64 * LW];
    __shared__ bf16 Vs[64 * LW];
    int t = threadIdx.x;
    int nh = blockIdx.x & 31, half = (blockIdx.x >> 5) & 1, qtile = blockIdx.x >> 6;
    int n = nh >> 3, h = nh & 7;
    int r0 = qtile * 64;
    int kt0 = half * 4;
    int w = t >> 6, quad = (t >> 4) & 3, c16 = t & 15;
    const bf16* Kb = Kp + (long)nh * 512 * 64;
    const bf16* Vb = Vtg + (long)nh * 64 * 512;

    // first-tile K/V prefetch (drains during q-proj)
    int prow0 = t >> 3, pcol0 = t & 7;
    int prow1 = (t + 256) >> 3, pcol1 = t & 7;
    bf16x8 pk0 = *(const bf16x8*)(Kb + (long)(kt0 * 64 + prow0) * 64 + pcol0 * 8);
    bf16x8 pk1 = *(const bf16x8*)(Kb + (long)(kt0 * 64 + prow1) * 64 + pcol1 * 8);
    bf16x8 pv0 = *(const bf16x8*)(Vb + (long)prow0 * 512 + kt0 * 64 + pcol0 * 8);
    bf16x8 pv1 = *(const bf16x8*)(Vb + (long)prow1 * 512 + kt0 * 64 + pcol1 * 8);

    // Wq fragments (scale folded); dead after q-proj
    bf16x8 wf[8];
#pragma unroll
    for (int nb = 0; nb < 4; ++nb)
#pragma unroll
        for (int kc = 0; kc < 2; ++kc)
            wf[nb * 2 + kc] = cvt8(Wq + (16 * nb + c16) * 64 + 32 * kc + quad * 8, QSCALE);

    // stage raw query rows 16w..16w+15 (wave-private: no barrier)
    {
        int l = t & 63;
        int rloc = 16 * w + (l >> 2);
        const float* qrow = query + ((long)n * 2048 + r0 + rloc) * 512 + h * 64;
#pragma unroll
        for (int j = 0; j < 4; ++j) {
            int c = (l & 3) + 4 * j;
            float4 a = *(const float4*)(qrow + c * 4);
            *(bf16x4*)&SX[rloc * LS + c * 4] = (bf16x4){(bf16)a.x, (bf16)a.y, (bf16)a.z, (bf16)a.w};
        }
    }
    // q-proj: 16 rows per wave, A-frags from wave-private SX rows
    f32x4 qa[4];
#pragma unroll
    for (int nb = 0; nb < 4; ++nb) qa[nb] = (f32x4){0.f, 0.f, 0.f, 0.f};
#pragma unroll
    for (int kc = 0; kc < 2; ++kc) {
        bf16x8 a = *(const bf16x8*)&SX[(16 * w + c16) * LS + 32 * kc + quad * 8];
#pragma unroll
        for (int nb = 0; nb < 4; ++nb)
            qa[nb] = __builtin_amdgcn_mfma_f32_16x16x32_bf16(a, wf[nb * 2 + kc], qa[nb], 0, 0, 0);
    }
    // Qt (C-layout) into SX, then hoist A-layout Q fragments to VGPRs
#pragma unroll
    for (int nb = 0; nb < 4; ++nb)
#pragma unroll
        for (int r = 0; r < 4; ++r)
            SX[(16 * w + quad * 4 + r) * LS + 16 * nb + c16] = (bf16)qa[nb][r];
    bf16x8 qf[2];
#pragma unroll
    for (int kc = 0; kc < 2; ++kc)
        qf[kc] = *(const bf16x8*)&SX[(16 * w + c16) * LS + 32 * kc + quad * 8];

    f32x4 oacc[4];
#pragma unroll
    for (int mb = 0; mb < 4; ++mb) oacc[mb] = (f32x4){0.f, 0.f, 0.f, 0.f};
    float ps = 0.f;

    for (int kt = 0; kt < 4; ++kt) {
        int tk = kt0 + kt;
        if (kt) __syncthreads();
        *(bf16x8*)&Kt[prow0 * LW + pcol0 * 8] = pk0;
        *(bf16x8*)&Kt[prow1 * LW + pcol1 * 8] = pk1;
        *(bf16x8*)&Vs[prow0 * LW + pcol0 * 8] = pv0;
        *(bf16x8*)&Vs[prow1 * LW + pcol1 * 8] = pv1;
        __syncthreads();
        if (kt < 3) {  // register prefetch of next tile
            pk0 = *(const bf16x8*)(Kb + (long)((tk + 1) * 64 + prow0) * 64 + pcol0 * 8);
            pk1 = *(const bf16x8*)(Kb + (long)((tk + 1) * 64 + prow1) * 64 + pcol1 * 8);
            pv0 = *(const bf16x8*)(Vb + (long)prow0 * 512 + (tk + 1) * 64 + pcol0 * 8);
            pv1 = *(const bf16x8*)(Vb + (long)prow1 * 512 + (tk + 1) * 64 + pcol1 * 8);
        }
        // mask bias as acc-init (int4 broadcast loads, 16B-aligned)
        f32x4 sc[4];
#pragma unroll
        for (int mb = 0; mb < 4; ++mb) {
            int4 mk = *(const int4*)(maskp + n * 512 + tk * 64 + 16 * mb + quad * 4);
            sc[mb] = (f32x4){mk.x ? 0.f : MASK_BIAS, mk.y ? 0.f : MASK_BIAS,
                             mk.z ? 0.f : MASK_BIAS, mk.w ? 0.f : MASK_BIAS};
        }
        // S^T = K.Q^T : m=key (4 blocks), n = this wave's 16 q-rows
#pragma unroll
        for (int kc = 0; kc < 2; ++kc) {
#pragma unroll
            for (int mb = 0; mb < 4; ++mb) {
                bf16x8 ka = *(const bf16x8*)&Kt[(16 * mb + c16) * LW + 32 * kc + quad * 8];
                sc[mb] = __builtin_amdgcn_mfma_f32_16x16x32_bf16(ka, qf[kc], sc[mb], 0, 0, 0);
            }
        }
        // p = exp2(s); l += p; P into wave-private SX rows [qrow][key]
#pragma unroll
        for (int mb = 0; mb < 4; ++mb) {
            float p0 = exp2f(sc[mb][0]);
            float p1 = exp2f(sc[mb][1]);
            float p2 = exp2f(sc[mb][2]);
            float p3 = exp2f(sc[mb][3]);
            ps += (p0 + p1) + (p2 + p3);
            *(bf16x4*)&SX[(16 * w + c16) * LS + 16 * mb + quad * 4] =
                (bf16x4){(bf16)p0, (bf16)p1, (bf16)p2, (bf16)p3};
        }
        // O^T += V.P^T (A=Vs shared, B=P wave-private)
#pragma unroll
        for (int kc = 0; kc < 2; ++kc) {
            bf16x8 pb = *(const bf16x8*)&SX[(16 * w + c16) * LS + 32 * kc + quad * 8];
#pragma unroll
            for (int mb = 0; mb < 4; ++mb) {
                bf16x8 va = *(const bf16x8*)&Vs[(16 * mb + c16) * LW + 32 * kc + quad * 8];
                oacc[mb] = __builtin_amdgcn_mfma_f32_16x16x32_bf16(va, pb, oacc[mb], 0, 0, 0);
            }
        }
    }
    // raw partial out: O^T (bf16) + l (f32). No normalization here.
    ps += __shfl_xor(ps, 16);
    ps += __shfl_xor(ps, 32);
    int row_g = r0 + 16 * w + c16;
    bf16* AO = AOp + (long)half * 4194304;
#pragma unroll
    for (int mb = 0; mb < 4; ++mb)
        *(bf16x4*)(AO + ((long)n * 2048 + row_g) * 512 + h * 64 + 16 * mb + quad * 4) =
            (bf16x4){(bf16)oacc[mb][0], (bf16)oacc[mb][1], (bf16)oacc[mb][2], (bf16)oacc[mb][3]};
    if (quad == 0) Lb[half * 65536 + nh * 2048 + row_g] = ps;
}

// ---------------------------------------------------------------- out_gemm
// C[8192][512] = combine(AO1,AO2,l) @ Wo^T + bo. grid 1024: br(128) INNER x
// bc(8). 64x64 tiles, block 256 (16 rows/wave), BK=64, register prefetch.
__global__ __launch_bounds__(256, 4) void out_gemm(const bf16* __restrict__ AOp,
                                                   const float* __restrict__ Lb,
                                                   const float* __restrict__ Wo,
                                                   const float* __restrict__ bo,
                                                   float* __restrict__ C) {
    __shared__ bf16 At[64 * LW];
    __shared__ bf16 Bt[64 * LW];
    int t = threadIdx.x;
    int br = blockIdx.x & 127, bc = blockIdx.x >> 7;
    int r0 = br * 64, c0 = bc * 64;
    int w = t >> 6, quad = (t >> 4) & 3, c16 = t & 15;
    const bf16* AO2 = AOp + 4194304;
    int arow[2], acol[2], wrow[4], wcol[4];
#pragma unroll
    for (int i = 0; i < 2; ++i) {
        int f = t + i * 256;  // 512 b128 slots over 64x8
        arow[i] = f >> 3;
        acol[i] = f & 7;
    }
#pragma unroll
    for (int i = 0; i < 4; ++i) {
        int f = t + i * 256;  // 1024 f4 slots over 64x16
        wrow[i] = f >> 4;
        wcol[i] = f & 15;
    }
    bf16x8 pa1[2], pa2[2];
    float4 pw[4];
#pragma unroll
    for (int i = 0; i < 2; ++i) {
        pa1[i] = *(const bf16x8*)(AOp + (long)(r0 + arow[i]) * 512 + acol[i] * 8);
        pa2[i] = *(const bf16x8*)(AO2 + (long)(r0 + arow[i]) * 512 + acol[i] * 8);
    }
#pragma unroll
    for (int i = 0; i < 4; ++i)
        pw[i] = *(const float4*)(Wo + (long)(c0 + wrow[i]) * 512 + wcol[i] * 4);
    f32x4 acc[4];
#pragma unroll
    for (int nb = 0; nb < 4; ++nb) acc[nb] = (f32x4){0.f, 0.f, 0.f, 0.f};
    for (int k0 = 0; k0 < 512; k0 += 64) {
        int hh = k0 >> 6;  // head is chunk-uniform -> per-row norm factor
        if (k0) __syncthreads();
#pragma unroll
        for (int i = 0; i < 2; ++i) {
            int grow = r0 + arow[i];
            int lidx = ((grow >> 11) * 8 + hh) * 2048 + (grow & 2047);
            float il = 1.0f / (Lb[lidx] + Lb[65536 + lidx]);
            bf16x8 o;
#pragma unroll
            for (int e = 0; e < 8; ++e)
                o[e] = (bf16)(((float)pa1[i][e] + (float)pa2[i][e]) * il);
            *(bf16x8*)&At[arow[i] * LW + acol[i] * 8] = o;
        }
#pragma unroll
        for (int i = 0; i < 4; ++i)
            *(bf16x4*)&Bt[wrow[i] * LW + wcol[i] * 4] =
                (bf16x4){(bf16)pw[i].x, (bf16)pw[i].y, (bf16)pw[i].z, (bf16)pw[i].w};
        __syncthreads();
        if (k0 < 448) {
#pragma unroll
            for (int i = 0; i < 2; ++i) {
                pa1[i] = *(const bf16x8*)(AOp + (long)(r0 + arow[i]) * 512 + k0 + 64 + acol[i] * 8);
                pa2[i] = *(const bf16x8*)(AO2 + (long)(r0 + arow[i]) * 512 + k0 + 64 + acol[i] * 8);
            }
#pragma unroll
            for (int i = 0; i < 4; ++i)
                pw[i] = *(const float4*)(Wo + (long)(c0 + wrow[i]) * 512 + k0 + 64 + wcol[i] * 4);
        }
#pragma unroll
        for (int kc = 0; kc < 2; ++kc) {
            bf16x8 a = *(const bf16x8*)&At[(16 * w + c16) * LW + 32 * kc + quad * 8];
#pragma unroll
            for (int nb = 0; nb < 4; ++nb) {
                bf16x8 b = *(const bf16x8*)&Bt[(16 * nb + c16) * LW + 32 * kc + quad * 8];
                acc[nb] = __builtin_amdgcn_mfma_f32_16x16x32_bf16(a, b, acc[nb], 0, 0, 0);
            }
        }
    }
#pragma unroll
    for (int nb = 0; nb < 4; ++nb) {
        float bias = bo[c0 + 16 * nb + c16];
#pragma unroll
        for (int r = 0; r < 4; ++r)
            C[(long)(r0 + 16 * w + quad * 4 + r) * 512 + c0 + 16 * nb + c16] = acc[nb][r] + bias;
    }
}

extern "C" void kernel_launch(void* const* d_in, const int* in_sizes, int n_in,
                              void* d_out, int out_size, void* d_ws, size_t ws_size,
                              hipStream_t stream) {
    const float* values = (const float*)d_in[0];
    const float* keys   = (const float*)d_in[1];
    const float* query  = (const float*)d_in[2];
    const int*   maskp  = (const int*)d_in[3];
    const float* Wv     = (const float*)d_in[4];
    const float* Wk     = (const float*)d_in[5];
    const float* Wq     = (const float*)d_in[6];
    const float* Wo     = (const float*)d_in[7];
    const float* bo     = (const float*)d_in[8];
    float* out = (float*)d_out;

    bf16* ws = (bf16*)d_ws;
    bf16* Kp  = ws;                 // 1,048,576 bf16
    bf16* Vt  = Kp + 1048576;       // 1,048,576
    bf16* AOp = Vt + 1048576;       // 2 x 4,194,304 (half 0 | half 1)
    float* Lb = (float*)(AOp + 8388608);  // 2 x 65,536 floats

    kv_proj<<<dim3(512), dim3(256), 0, stream>>>(keys, values, Wk, Wv, Kp, Vt);
    attn<<<dim3(2048), dim3(256), 0, stream>>>(query, Wq, Kp, Vt, maskp, AOp, Lb);
    out_gemm<<<dim3(1024), dim3(256), 0, stream>>>(AOp, Lb, Wo, bo, out);
}